// Round 2
// baseline (407.841 us; speedup 1.0000x reference)
//
#include <hip/hip_runtime.h>
#include <stdint.h>

#define G  128
#define TT 96
#define NB 2
#define NC 4
#define CS (TT * TT * TT)

// Prepass: template [B,C,z,y,x] fp32 -> channels-last float4 [B,z,y,x] (16B/voxel)
__global__ __launch_bounds__(256) void tmpl_repack_kernel(
        const float* __restrict__ tmpl, float4* __restrict__ out) {
    const int NV = NB * CS;
    int idx = blockIdx.x * 256 + threadIdx.x;
    if (idx >= NV) return;
    int b = idx / CS;
    int s = idx - b * CS;
    const float* base = tmpl + (size_t)b * NC * CS + s;
    float4 p;
    p.x = base[0];
    p.y = base[CS];
    p.z = base[2 * CS];
    p.w = base[3 * CS];
    out[idx] = p;
}

// One block = tile of 32(d) x 32(w) at fixed (b, h).
// stage1: deformation[b,c,w,h,d] (d-contig) -> LDS, float4 loads
// stage2: grids[b,d,h,w,3] ((w,c)-contig) + LDS def -> tanh field in LDS; write defp
// stage3: trilinear gather; write out2[b,c,w,h,d] (d-contig) + correction
template <bool PACKED>
__global__ __launch_bounds__(256) void fused_sample_kernel(
        const float* __restrict__ grids,
        const float* __restrict__ deform,
        const float* __restrict__ corr,
        const float4* __restrict__ tmpl_cl,   // used when PACKED
        const float* __restrict__ tmpl_raw,   // used when !PACKED
        float* __restrict__ out2,
        float* __restrict__ defp) {
    __shared__ float lds_def[3][32][33];    // [c][i=w][j=d] (+1 pad)
    __shared__ float lds_field[3][32][33];  // [c][j=d][i=w] (+1 pad)

    int blk = blockIdx.x;
    int wt = blk & 3;
    int dt = (blk >> 2) & 3;
    int h  = (blk >> 4) & 127;
    int b  = blk >> 11;
    int w0 = wt << 5, d0 = dt << 5;
    int tid = threadIdx.x;

    // ---- stage 1: deformation -> lds_def[c][i][j], 16B vector loads along d
    for (int idx = tid; idx < 768; idx += 256) {   // 3c * 32i * 8 quads
        int c   = idx >> 8;
        int rem = idx & 255;
        int i   = rem >> 3;
        int j4  = (rem & 7) << 2;
        size_t off = ((((size_t)b * 3 + c) * G + (w0 + i)) * G + h) * G + (d0 + j4);
        float4 v = *(const float4*)(deform + off);   // off % 4 == 0 -> 16B aligned
        lds_def[c][i][j4 + 0] = v.x;
        lds_def[c][i][j4 + 1] = v.y;
        lds_def[c][i][j4 + 2] = v.z;
        lds_def[c][i][j4 + 3] = v.w;
    }
    __syncthreads();

    // ---- stage 2: grids row (96 floats contiguous in (w,c)) -> field; defp write
    for (int idx = tid; idx < 768; idx += 256) {   // 32 rows * 24 float4-chunks
        int j = idx / 24;
        int t = idx - j * 24;
        size_t off = (((((size_t)b * G + (d0 + j)) * G + h) * G + w0) * 3) + (size_t)t * 4;
        float gv[4], dv[4];
        *(float4*)gv = *(const float4*)(grids + off);  // off % 4 == 0 (w0 mult of 32)
#pragma unroll
        for (int k = 0; k < 4; ++k) {
            int e = t * 4 + k;
            int i = e / 3;
            int c = e - 3 * i;
            float d = lds_def[c][i][j];
            lds_field[c][j][i] = tanhf(gv[k] + d);
            dv[k] = d;                                  // exact pass-through
        }
        *(float4*)(defp + off) = *(float4*)dv;
    }
    __syncthreads();

    // ---- stage 3: trilinear sample + correction, out2 d-contig across threads
    const float SC = 0.5f * (TT - 1);
    for (int p = tid; p < 1024; p += 256) {
        int i = p >> 5;        // w offset
        int j = p & 31;        // d offset
        float ix = (lds_field[0][j][i] + 1.0f) * SC;
        float iy = (lds_field[1][j][i] + 1.0f) * SC;
        float iz = (lds_field[2][j][i] + 1.0f) * SC;
        float x0f = floorf(ix), y0f = floorf(iy), z0f = floorf(iz);
        float wx = ix - x0f, wy = iy - y0f, wz = iz - z0f;
        int x0 = min(max((int)x0f, 0), TT - 1);
        int y0 = min(max((int)y0f, 0), TT - 1);
        int z0 = min(max((int)z0f, 0), TT - 1);
        int x1 = min(x0 + 1, TT - 1);
        int y1 = min(y0 + 1, TT - 1);
        int z1 = min(z0 + 1, TT - 1);
        float mx = 1.0f - wx, my = 1.0f - wy, mz = 1.0f - wz;
        float w000 = mx * my * mz, w001 = wx * my * mz;
        float w010 = mx * wy * mz, w011 = wx * wy * mz;
        float w100 = mx * my * wz, w101 = wx * my * wz;
        float w110 = mx * wy * wz, w111 = wx * wy * wz;

        float r0, r1, r2, r3;
        if (PACKED) {
            const float4* tb = tmpl_cl + (size_t)b * CS;
            float4 v000 = tb[((size_t)z0 * TT + y0) * TT + x0];
            float4 v001 = tb[((size_t)z0 * TT + y0) * TT + x1];
            float4 v010 = tb[((size_t)z0 * TT + y1) * TT + x0];
            float4 v011 = tb[((size_t)z0 * TT + y1) * TT + x1];
            float4 v100 = tb[((size_t)z1 * TT + y0) * TT + x0];
            float4 v101 = tb[((size_t)z1 * TT + y0) * TT + x1];
            float4 v110 = tb[((size_t)z1 * TT + y1) * TT + x0];
            float4 v111 = tb[((size_t)z1 * TT + y1) * TT + x1];
            r0 = v000.x*w000 + v001.x*w001 + v010.x*w010 + v011.x*w011
               + v100.x*w100 + v101.x*w101 + v110.x*w110 + v111.x*w111;
            r1 = v000.y*w000 + v001.y*w001 + v010.y*w010 + v011.y*w011
               + v100.y*w100 + v101.y*w101 + v110.y*w110 + v111.y*w111;
            r2 = v000.z*w000 + v001.z*w001 + v010.z*w010 + v011.z*w011
               + v100.z*w100 + v101.z*w101 + v110.z*w110 + v111.z*w111;
            r3 = v000.w*w000 + v001.w*w001 + v010.w*w010 + v011.w*w011
               + v100.w*w100 + v101.w*w101 + v110.w*w110 + v111.w*w111;
        } else {
            size_t i000 = ((size_t)z0 * TT + y0) * TT + x0;
            size_t i001 = ((size_t)z0 * TT + y0) * TT + x1;
            size_t i010 = ((size_t)z0 * TT + y1) * TT + x0;
            size_t i011 = ((size_t)z0 * TT + y1) * TT + x1;
            size_t i100 = ((size_t)z1 * TT + y0) * TT + x0;
            size_t i101 = ((size_t)z1 * TT + y0) * TT + x1;
            size_t i110 = ((size_t)z1 * TT + y1) * TT + x0;
            size_t i111 = ((size_t)z1 * TT + y1) * TT + x1;
            float rr[4];
#pragma unroll
            for (int c = 0; c < NC; ++c) {
                const float* tb = tmpl_raw + ((size_t)b * NC + c) * CS;
                rr[c] = tb[i000]*w000 + tb[i001]*w001 + tb[i010]*w010 + tb[i011]*w011
                      + tb[i100]*w100 + tb[i101]*w101 + tb[i110]*w110 + tb[i111]*w111;
            }
            r0 = rr[0]; r1 = rr[1]; r2 = rr[2]; r3 = rr[3];
        }

        int w = w0 + i, d = d0 + j;
        size_t obase = ((((size_t)b * NC) * (size_t)G + w) * G + h) * G + d;
        const size_t cstride = (size_t)G * G * G;
        out2[obase + 0 * cstride] = r0 + corr[obase + 0 * cstride];
        out2[obase + 1 * cstride] = r1 + corr[obase + 1 * cstride];
        out2[obase + 2 * cstride] = r2 + corr[obase + 2 * cstride];
        out2[obase + 3 * cstride] = r3 + corr[obase + 3 * cstride];
    }
}

extern "C" void kernel_launch(void* const* d_in, const int* in_sizes, int n_in,
                              void* d_out, int out_size, void* d_ws, size_t ws_size,
                              hipStream_t stream) {
    const float* grids  = (const float*)d_in[0];
    const float* deform = (const float*)d_in[1];
    const float* corr   = (const float*)d_in[2];
    const float* tmpl   = (const float*)d_in[3];
    float* out2 = (float*)d_out;
    float* defp = out2 + (size_t)NB * NC * G * G * G;   // outputs concatenated flat
    float4* tmpl_cl = (float4*)d_ws;

    const size_t ws_needed = (size_t)NB * CS * sizeof(float4);  // 28.3 MB
    const bool packed = (ws_size >= ws_needed);

    if (packed) {
        int nv = NB * CS;
        tmpl_repack_kernel<<<(nv + 255) / 256, 256, 0, stream>>>(tmpl, tmpl_cl);
    }

    int nblk = NB * G * 16;   // (b,h) * 4 w-tiles * 4 d-tiles = 4096 blocks
    if (packed) {
        fused_sample_kernel<true><<<nblk, 256, 0, stream>>>(
            grids, deform, corr, tmpl_cl, tmpl, out2, defp);
    } else {
        fused_sample_kernel<false><<<nblk, 256, 0, stream>>>(
            grids, deform, corr, tmpl_cl, tmpl, out2, defp);
    }
}